// Round 10
// baseline (175.071 us; speedup 1.0000x reference)
//
#include <hip/hip_runtime.h>

#define DD   32
#define HH   256
#define BB   4096
#define RR   2      // rows per wave
#define EPSF 1e-12f

// ---------------------------------------------------------------------------
// Degree-sorted layout. deg_h[h] = (h%31)+1. Counts: deg 1..8 -> 9, 9..31 -> 8.
// Sorted position p -> original h:
//   p < 72:  h = (p/9) + 31*(p%9)
//   p >= 72: h = (8+(p-72)/8) + 31*((p-72)%8)
// Group deg==d occupies sorted positions [OFF(d), OFF(d+1)),
//   OFF(d) = (d<=9) ? 9*(d-1) : 8*d   (d>=1; OFF(1)=0, OFF(32)=256)
// ---------------------------------------------------------------------------
__device__ __forceinline__ int made_pi(int p) {
    return (p < 72) ? (p / 9) + 31 * (p % 9)
                    : (8 + (p - 72) / 8) + 31 * ((p - 72) % 8);
}
__device__ __forceinline__ int made_off(int d) {   // d >= 1
    return (d <= 9) ? 9 * (d - 1) : 8 * d;
}

// ws float layout:
//   per net n (n=0 mu, n=1 lv), base n*NETF:
//     W0s[32][256] @0 | W1s[256][256] @8192 | b0s[256] @73728 | b1s[256] @73984
//   shared W2i[256][2][32] @ 2*NETF   (W2i[p][n][dd] = Wn2[h(p)][dd])
#define NW0   (DD * HH)                 // 8192
#define NW1   (HH * HH)                 // 65536
#define NETF  (NW0 + NW1 + HH + HH)     // 74240
#define W2IOFF (2 * NETF)
#define NW2I  (HH * 64)                 // 16384
#define WSNEED ((size_t)(W2IOFF + NW2I) * 4)

// ---------------------------------------------------------------------------
// Prep: blocks 0..511 -> W1 rows (LDS-staged permute) + biases;
//       blocks 512..767 -> W2i rows; blocks 768..831 -> W0 rows.
// ---------------------------------------------------------------------------
__global__ void made_prep(
    const float* __restrict__ muW0, const float* __restrict__ mub0,
    const float* __restrict__ muW1, const float* __restrict__ mub1,
    const float* __restrict__ muW2,
    const float* __restrict__ lvW0, const float* __restrict__ lvb0,
    const float* __restrict__ lvW1, const float* __restrict__ lvb1,
    const float* __restrict__ lvW2,
    float* __restrict__ ws)
{
    const int t = threadIdx.x;           // 0..63
    const int b = blockIdx.x;
    __shared__ float rowbuf[HH];

    if (b < 512) {
        const int n = b >> 8, p = b & 255;
        const int h = made_pi(p);
        const float* W1 = n ? lvW1 : muW1;
        float* o = ws + (size_t)n * NETF;
        *reinterpret_cast<float4*>(&rowbuf[4 * t]) =
            *reinterpret_cast<const float4*>(W1 + h * HH + 4 * t);
        __syncthreads();
        float4 w;
        w.x = rowbuf[made_pi(4 * t + 0)];
        w.y = rowbuf[made_pi(4 * t + 1)];
        w.z = rowbuf[made_pi(4 * t + 2)];
        w.w = rowbuf[made_pi(4 * t + 3)];
        *reinterpret_cast<float4*>(o + NW0 + p * HH + 4 * t) = w;
        if (t == 0) {
            o[NW0 + NW1 + p]      = (n ? lvb0 : mub0)[h];
            o[NW0 + NW1 + HH + p] = (n ? lvb1 : mub1)[h];
        }
    } else if (b < 768) {
        const int p = b - 512;           // sorted position
        const int h = made_pi(p);
        const int n = t >> 5, dd = t & 31;
        ws[W2IOFF + p * 64 + t] = (n ? lvW2 : muW2)[h * DD + dd];
    } else {
        const int idx = b - 768;         // 0..63
        const int n = idx >> 5, i = idx & 31;
        const float* W0 = n ? lvW0 : muW0;
        float* o = ws + (size_t)n * NETF;
        *reinterpret_cast<float4*>(&rowbuf[4 * t]) =
            *reinterpret_cast<const float4*>(W0 + i * HH + 4 * t);
        __syncthreads();
        float4 w;
        w.x = rowbuf[made_pi(4 * t + 0)];
        w.y = rowbuf[made_pi(4 * t + 1)];
        w.z = rowbuf[made_pi(4 * t + 2)];
        w.w = rowbuf[made_pi(4 * t + 3)];
        *reinterpret_cast<float4*>(o + i * HH + 4 * t) = w;
    }
}

// ---------------------------------------------------------------------------
// Main, R10: R7 structure (per-wave direct loads, barrier-free) +
//  - software pipeline: step d+1's weights are loaded right AFTER step d's
//    h1 consumption (last use of current w1 regs -> no live-range doubling),
//    so loads get the whole Bf/acc/output stage (~300 cyc) to land.
//    Unconditional, clamped indices (no runtime guards -> no scratch).
//  - divide replaced by exp(-x) multiply (shorter serial output chain).
//  - 64-thread single-wave blocks, 2048 blocks (finer scheduling, less tail).
// ---------------------------------------------------------------------------
__global__ __launch_bounds__(64, 2) void made_main(
    const float* __restrict__ ws, const float* __restrict__ x,
    const float* __restrict__ mub2, const float* __restrict__ lvb2,
    float* __restrict__ out)
{
    const int lane = threadIdx.x;        // 0..63 (single wave per block)
    const int row0 = blockIdx.x * RR;
    const int c4   = lane << 2;          // base sorted position (4 slots/lane)
    const int nn   = lane >> 5;          // net of this lane's output acc
    const int ddl  = lane & 31;          // output dim of this lane's acc

    const float* W0p[2] = {ws,       ws + NETF};
    const float* W1p[2] = {ws + NW0, ws + NETF + NW0};
    const float* W2i    = ws + W2IOFF;

    __shared__ float A [2][RR][12];      // relu(h0) of finalizing group
    __shared__ float Bf[2][RR][12];      // relu(h1) of finalizing group

    float h0[2][4][RR], h1[2][4][RR];
    #pragma unroll
    for (int n = 0; n < 2; ++n) {
        const float* bb = ws + (size_t)n * NETF + NW0 + NW1;
        const float4 v0 = *reinterpret_cast<const float4*>(bb + c4);
        const float4 v1 = *reinterpret_cast<const float4*>(bb + HH + c4);
        const float a0[4] = {v0.x, v0.y, v0.z, v0.w};
        const float a1[4] = {v1.x, v1.y, v1.z, v1.w};
        #pragma unroll
        for (int s = 0; s < 4; ++s)
            #pragma unroll
            for (int r = 0; r < RR; ++r) { h0[n][s][r] = a0[s]; h1[n][s][r] = a1[s]; }
    }

    const float accinit = nn ? lvb2[ddl] : mub2[ddl];
    float acc[RR];
    #pragma unroll
    for (int r = 0; r < RR; ++r) acc[r] = accinit;

    float xvr[RR];
    #pragma unroll
    for (int r = 0; r < RR; ++r) xvr[r] = x[(row0 + r) * DD + ddl];

    float yprev[RR], lsum[RR], ysave[RR];
    #pragma unroll
    for (int r = 0; r < RR; ++r) { lsum[r] = 0.f; ysave[r] = 0.f; }

    // ---- step d = 0 (acc == b2) ----
    #pragma unroll
    for (int r = 0; r < RR; ++r) {
        const float mu  = __shfl(acc[r], 0, 64);
        const float lv  = __shfl(acc[r], 32, 64);
        const float ls2 = 0.5f * lv;
        lsum[r] += ls2;
        const float yd = (__shfl(xvr[r], 0, 64) - mu) * __expf(-ls2);
        yprev[r] = yd;
        if (lane == 0) ysave[r] = yd;
    }

    // ---- prologue: load step-1 weights (off=0, rows 0..8 all valid) ----
    float4 w0m, w0l, w1m[9], w1l[9];
    float  w2[9];
    {
        w0m = *reinterpret_cast<const float4*>(W0p[0] + c4);
        w0l = *reinterpret_cast<const float4*>(W0p[1] + c4);
        #pragma unroll
        for (int k = 0; k < 9; ++k) {
            w1m[k] = *reinterpret_cast<const float4*>(W1p[0] + k * HH + c4);
            w1l[k] = *reinterpret_cast<const float4*>(W1p[1] + k * HH + c4);
            w2[k]  = W2i[k * 64 + lane];
        }
    }

    for (int d = 1; d < DD; ++d) {
        const int off = made_off(d);
        const int nk  = (d <= 8) ? 9 : 8;

        // ===== h0 += y_{d-1} * W0s[d-1,:] ==================================
        #pragma unroll
        for (int r = 0; r < RR; ++r) {
            h0[0][0][r] = fmaf(yprev[r], w0m.x, h0[0][0][r]);
            h0[0][1][r] = fmaf(yprev[r], w0m.y, h0[0][1][r]);
            h0[0][2][r] = fmaf(yprev[r], w0m.z, h0[0][2][r]);
            h0[0][3][r] = fmaf(yprev[r], w0m.w, h0[0][3][r]);
            h0[1][0][r] = fmaf(yprev[r], w0l.x, h0[1][0][r]);
            h0[1][1][r] = fmaf(yprev[r], w0l.y, h0[1][1][r]);
            h0[1][2][r] = fmaf(yprev[r], w0l.z, h0[1][2][r]);
            h0[1][3][r] = fmaf(yprev[r], w0l.w, h0[1][3][r]);
        }

        // zero the k=8 broadcast slots when the group has only 8 members
        if (d >= 9 && lane == 0) {
            #pragma unroll
            for (int n = 0; n < 2; ++n)
                #pragma unroll
                for (int r = 0; r < RR; ++r) {
                    A[n][r][8]  = 0.f;
                    Bf[n][r][8] = 0.f;
                }
        }
        // finalize relu(h0) -> A (only the nk members of group d)
        #pragma unroll
        for (int s = 0; s < 4; ++s) {
            const int k = c4 + s - off;
            if ((unsigned)k < (unsigned)nk) {
                #pragma unroll
                for (int r = 0; r < RR; ++r) {
                    A[0][r][k] = fmaxf(h0[0][s][r], 0.f);
                    A[1][r][k] = fmaxf(h0[1][s][r], 0.f);
                }
            }
        }
        // read broadcast av (wave-private LDS, program order)
        float av[2][RR][9];
        #pragma unroll
        for (int n = 0; n < 2; ++n)
            #pragma unroll
            for (int r = 0; r < RR; ++r) {
                const float4 a03 = *reinterpret_cast<const float4*>(&A[n][r][0]);
                const float4 a47 = *reinterpret_cast<const float4*>(&A[n][r][4]);
                av[n][r][0] = a03.x; av[n][r][1] = a03.y;
                av[n][r][2] = a03.z; av[n][r][3] = a03.w;
                av[n][r][4] = a47.x; av[n][r][5] = a47.y;
                av[n][r][6] = a47.z; av[n][r][7] = a47.w;
                av[n][r][8] = A[n][r][8];
            }

        // ===== h1 += av[k] * W1s[row k] — uniform 9 (LAST USE of w1 regs) ==
        #pragma unroll
        for (int k = 0; k < 9; ++k) {
            #pragma unroll
            for (int r = 0; r < RR; ++r) {
                h1[0][0][r] = fmaf(av[0][r][k], w1m[k].x, h1[0][0][r]);
                h1[0][1][r] = fmaf(av[0][r][k], w1m[k].y, h1[0][1][r]);
                h1[0][2][r] = fmaf(av[0][r][k], w1m[k].z, h1[0][2][r]);
                h1[0][3][r] = fmaf(av[0][r][k], w1m[k].w, h1[0][3][r]);
                h1[1][0][r] = fmaf(av[1][r][k], w1l[k].x, h1[1][0][r]);
                h1[1][1][r] = fmaf(av[1][r][k], w1l[k].y, h1[1][1][r]);
                h1[1][2][r] = fmaf(av[1][r][k], w1l[k].z, h1[1][2][r]);
                h1[1][3][r] = fmaf(av[1][r][k], w1l[k].w, h1[1][3][r]);
            }
        }

        // ===== pipeline: issue step d+1's loads now (clamped; last iter
        //       redundantly reloads step 31 — branch-free, no guards) ======
        const int dn   = (d < DD - 1) ? d + 1 : DD - 1;
        const int offN = made_off(dn);
        int r8n = offN + 8; if (r8n > 255) r8n = 255;
        float4 nw0m = *reinterpret_cast<const float4*>(W0p[0] + (dn - 1) * HH + c4);
        float4 nw0l = *reinterpret_cast<const float4*>(W0p[1] + (dn - 1) * HH + c4);
        float4 nw1m[9], nw1l[9];
        float  nw2[9];
        #pragma unroll
        for (int k = 0; k < 8; ++k) {
            nw1m[k] = *reinterpret_cast<const float4*>(W1p[0] + (offN + k) * HH + c4);
            nw1l[k] = *reinterpret_cast<const float4*>(W1p[1] + (offN + k) * HH + c4);
            nw2[k]  = W2i[(offN + k) * 64 + lane];
        }
        nw1m[8] = *reinterpret_cast<const float4*>(W1p[0] + r8n * HH + c4);
        nw1l[8] = *reinterpret_cast<const float4*>(W1p[1] + r8n * HH + c4);
        nw2[8]  = W2i[r8n * 64 + lane];

        // ===== finalize relu(h1) -> Bf (only the nk members of group d) ====
        #pragma unroll
        for (int s = 0; s < 4; ++s) {
            const int k = c4 + s - off;
            if ((unsigned)k < (unsigned)nk) {
                #pragma unroll
                for (int r = 0; r < RR; ++r) {
                    Bf[0][r][k] = fmaxf(h1[0][s][r], 0.f);
                    Bf[1][r][k] = fmaxf(h1[1][s][r], 0.f);
                }
            }
        }
        // fold finalized relu(h1) into output accumulators
        float rb[RR][9];
        #pragma unroll
        for (int r = 0; r < RR; ++r) {
            const float4 b03 = *reinterpret_cast<const float4*>(&Bf[nn][r][0]);
            const float4 b47 = *reinterpret_cast<const float4*>(&Bf[nn][r][4]);
            rb[r][0] = b03.x; rb[r][1] = b03.y; rb[r][2] = b03.z; rb[r][3] = b03.w;
            rb[r][4] = b47.x; rb[r][5] = b47.y; rb[r][6] = b47.z; rb[r][7] = b47.w;
            rb[r][8] = Bf[nn][r][8];
        }
        #pragma unroll
        for (int k = 0; k < 9; ++k)
            #pragma unroll
            for (int r = 0; r < RR; ++r)
                acc[r] = fmaf(rb[r][k], w2[k], acc[r]);

        // ===== outputs for dim d (exp-mul: (x-mu)*exp(-ls); eps ~1e-12
        //       relative — far below the 8.75e-2 tolerance) ================
        #pragma unroll
        for (int r = 0; r < RR; ++r) {
            const float mu  = __shfl(acc[r], d, 64);
            const float lv  = __shfl(acc[r], 32 + d, 64);
            const float ls2 = 0.5f * lv;
            lsum[r] += ls2;
            const float yd = (__shfl(xvr[r], d, 64) - mu) * __expf(-ls2);
            yprev[r] = yd;
            if (lane == d) ysave[r] = yd;
        }

        // ===== rotate pipeline registers (pure renames after SSA) ==========
        w0m = nw0m; w0l = nw0l;
        #pragma unroll
        for (int k = 0; k < 9; ++k) {
            w1m[k] = nw1m[k]; w1l[k] = nw1l[k]; w2[k] = nw2[k];
        }
    }

    #pragma unroll
    for (int r = 0; r < RR; ++r) {
        if (lane < DD) out[(row0 + r) * DD + lane] = ysave[r];   // coalesced
        if (lane == 0) out[BB * DD + row0 + r] = lsum[r];
    }
}

// ---------------------------------------------------------------------------
// Fallback (no workspace): R1-style kernel.
// ---------------------------------------------------------------------------
__global__ __launch_bounds__(64, 1) void made_inv_fb(
    const float* __restrict__ x,
    const float* __restrict__ muW0, const float* __restrict__ mub0,
    const float* __restrict__ muW1, const float* __restrict__ mub1,
    const float* __restrict__ muW2, const float* __restrict__ mub2,
    const float* __restrict__ lvW0, const float* __restrict__ lvb0,
    const float* __restrict__ lvW1, const float* __restrict__ lvb1,
    const float* __restrict__ lvW2, const float* __restrict__ lvb2,
    float* __restrict__ out)
{
    const int lane    = threadIdx.x;
    const int rowBase = blockIdx.x * 4;
    const int hb      = lane << 2;
    int deg[4];
    #pragma unroll
    for (int s = 0; s < 4; ++s) deg[s] = ((hb + s) % 31) + 1;
    const float* Wp0[2] = {muW0, lvW0};
    const float* Bp0[2] = {mub0, lvb0};
    const float* Wp1[2] = {muW1, lvW1};
    const float* Bp1[2] = {mub1, lvb1};
    const float* Wp2[2] = {muW2, lvW2};
    float h0pre[2][4][4], h1pre[2][4][4], r1[2][4][4], yprev[4], lsum[4];
    #pragma unroll
    for (int n = 0; n < 2; ++n) {
        const float4 b0v = *reinterpret_cast<const float4*>(Bp0[n] + hb);
        const float4 b1v = *reinterpret_cast<const float4*>(Bp1[n] + hb);
        const float b0a[4] = {b0v.x, b0v.y, b0v.z, b0v.w};
        const float b1a[4] = {b1v.x, b1v.y, b1v.z, b1v.w};
        #pragma unroll
        for (int s = 0; s < 4; ++s)
            #pragma unroll
            for (int r = 0; r < 4; ++r) {
                h0pre[n][s][r] = b0a[s]; h1pre[n][s][r] = b1a[s]; r1[n][s][r] = 0.f;
            }
    }
    #pragma unroll
    for (int r = 0; r < 4; ++r) { yprev[r] = 0.f; lsum[r] = 0.f; }
    __shared__ float lds_a[2][4][12];
    for (int d = 0; d < DD; ++d) {
        if (d >= 1) {
            #pragma unroll
            for (int n = 0; n < 2; ++n) {
                const float4 w0 = *reinterpret_cast<const float4*>(Wp0[n] + (d - 1) * HH + hb);
                const float w0a[4] = {w0.x, w0.y, w0.z, w0.w};
                #pragma unroll
                for (int s = 0; s < 4; ++s)
                    #pragma unroll
                    for (int r = 0; r < 4; ++r)
                        h0pre[n][s][r] = fmaf(yprev[r], w0a[s], h0pre[n][s][r]);
            }
            #pragma unroll
            for (int n = 0; n < 2; ++n)
                #pragma unroll
                for (int s = 0; s < 4; ++s)
                    if (deg[s] == d) {
                        const int k = (hb + s - (d - 1)) / 31;
                        #pragma unroll
                        for (int r = 0; r < 4; ++r)
                            lds_a[n][r][k] = fmaxf(h0pre[n][s][r], 0.f);
                    }
            __syncthreads();
            const bool nine = (d <= 8);
            #pragma unroll
            for (int n = 0; n < 2; ++n) {
                const float* W1r = Wp1[n] + (size_t)(d - 1) * HH + hb;
                float4 w1v[9];
                #pragma unroll
                for (int k = 0; k < 8; ++k)
                    w1v[k] = *reinterpret_cast<const float4*>(W1r + k * 31 * HH);
                if (nine) w1v[8] = *reinterpret_cast<const float4*>(W1r + 8 * 31 * HH);
                #pragma unroll
                for (int r = 0; r < 4; ++r) {
                    const float4 a03 = *reinterpret_cast<const float4*>(&lds_a[n][r][0]);
                    const float4 a47 = *reinterpret_cast<const float4*>(&lds_a[n][r][4]);
                    const float av[8] = {a03.x, a03.y, a03.z, a03.w, a47.x, a47.y, a47.z, a47.w};
                    #pragma unroll
                    for (int k = 0; k < 8; ++k) {
                        const float wk[4] = {w1v[k].x, w1v[k].y, w1v[k].z, w1v[k].w};
                        #pragma unroll
                        for (int s = 0; s < 4; ++s)
                            h1pre[n][s][r] = fmaf(av[k], wk[s], h1pre[n][s][r]);
                    }
                    if (nine) {
                        const float a8 = lds_a[n][r][8];
                        const float wk[4] = {w1v[8].x, w1v[8].y, w1v[8].z, w1v[8].w};
                        #pragma unroll
                        for (int s = 0; s < 4; ++s)
                            h1pre[n][s][r] = fmaf(a8, wk[s], h1pre[n][s][r]);
                    }
                }
            }
            #pragma unroll
            for (int n = 0; n < 2; ++n)
                #pragma unroll
                for (int s = 0; s < 4; ++s)
                    if (deg[s] == d)
                        #pragma unroll
                        for (int r = 0; r < 4; ++r)
                            r1[n][s][r] = fmaxf(h1pre[n][s][r], 0.f);
            __syncthreads();
        }
        float w2v[2][4];
        #pragma unroll
        for (int n = 0; n < 2; ++n)
            #pragma unroll
            for (int s = 0; s < 4; ++s)
                w2v[n][s] = Wp2[n][(hb + s) * DD + d];
        float red[2][4];
        #pragma unroll
        for (int n = 0; n < 2; ++n)
            #pragma unroll
            for (int r = 0; r < 4; ++r) {
                float p = 0.f;
                #pragma unroll
                for (int s = 0; s < 4; ++s) p = fmaf(r1[n][s][r], w2v[n][s], p);
                red[n][r] = p;
            }
        #pragma unroll
        for (int m = 1; m < 64; m <<= 1)
            #pragma unroll
            for (int n = 0; n < 2; ++n)
                #pragma unroll
                for (int r = 0; r < 4; ++r)
                    red[n][r] += __shfl_xor(red[n][r], m, 64);
        const float b2m = mub2[d], b2l = lvb2[d];
        #pragma unroll
        for (int r = 0; r < 4; ++r) {
            const float mu = red[0][r] + b2m;
            const float logstd = 0.5f * (red[1][r] + b2l);
            lsum[r] += logstd;
            const float yd = (x[(rowBase + r) * DD + d] - mu) / (__expf(logstd) + EPSF);
            yprev[r] = yd;
            if (lane == 0) out[(rowBase + r) * DD + d] = yd;
        }
    }
    if (lane == 0)
        #pragma unroll
        for (int r = 0; r < 4; ++r) out[BB * DD + rowBase + r] = lsum[r];
}

extern "C" void kernel_launch(void* const* d_in, const int* in_sizes, int n_in,
                              void* d_out, int out_size, void* d_ws, size_t ws_size,
                              hipStream_t stream) {
    const float* x    = (const float*)d_in[0];
    const float* muW0 = (const float*)d_in[1];
    const float* mub0 = (const float*)d_in[2];
    const float* muW1 = (const float*)d_in[3];
    const float* mub1 = (const float*)d_in[4];
    const float* muW2 = (const float*)d_in[5];
    const float* mub2 = (const float*)d_in[6];
    const float* lvW0 = (const float*)d_in[7];
    const float* lvb0 = (const float*)d_in[8];
    const float* lvW1 = (const float*)d_in[9];
    const float* lvb1 = (const float*)d_in[10];
    const float* lvW2 = (const float*)d_in[11];
    const float* lvb2 = (const float*)d_in[12];
    float* out = (float*)d_out;

    if (ws_size >= WSNEED) {
        float* ws = (float*)d_ws;
        made_prep<<<dim3(832), dim3(64), 0, stream>>>(
            muW0, mub0, muW1, mub1, muW2,
            lvW0, lvb0, lvW1, lvb1, lvW2, ws);
        made_main<<<dim3(BB / RR), dim3(64), 0, stream>>>(ws, x, mub2, lvb2, out);
    } else {
        made_inv_fb<<<dim3(BB / 4), dim3(64), 0, stream>>>(x,
            muW0, mub0, muW1, mub1, muW2, mub2,
            lvW0, lvb0, lvW1, lvb1, lvW2, lvb2, out);
    }
}

// Round 11
// 137.214 us; speedup vs baseline: 1.2759x; 1.2759x over previous
//
#include <hip/hip_runtime.h>

#define DD   32
#define HH   256
#define BB   4096
#define RR   2      // rows per wave
#define EPSF 1e-12f

// ---------------------------------------------------------------------------
// Degree-sorted layout. deg_h[h] = (h%31)+1. Counts: deg 1..8 -> 9, 9..31 -> 8.
// Sorted position p -> original h:
//   p < 72:  h = (p/9) + 31*(p%9)
//   p >= 72: h = (8+(p-72)/8) + 31*((p-72)%8)
// Group deg==d occupies sorted positions [OFF(d), OFF(d+1)),
//   OFF(d) = (d<=9) ? 9*(d-1) : 8*d   (d>=1; OFF(1)=0, OFF(32)=256)
// ---------------------------------------------------------------------------
__device__ __forceinline__ int made_pi(int p) {
    return (p < 72) ? (p / 9) + 31 * (p % 9)
                    : (8 + (p - 72) / 8) + 31 * ((p - 72) % 8);
}
__device__ __forceinline__ int made_off(int d) {   // d >= 1
    return (d <= 9) ? 9 * (d - 1) : 8 * d;
}

// ws float layout:
//   per net n (n=0 mu, n=1 lv), base n*NETF:
//     W0s[32][256] @0 | W1s[256][256] @8192 | b0s[256] @73728 | b1s[256] @73984
//   shared W2i[256][2][32] @ 2*NETF   (W2i[p][n][dd] = Wn2[h(p)][dd])
#define NW0   (DD * HH)                 // 8192
#define NW1   (HH * HH)                 // 65536
#define NETF  (NW0 + NW1 + HH + HH)     // 74240
#define W2IOFF (2 * NETF)
#define NW2I  (HH * 64)                 // 16384
#define WSNEED ((size_t)(W2IOFF + NW2I) * 4)

// ---------------------------------------------------------------------------
// Prep: blocks 0..511 -> W1 rows (LDS-staged permute) + biases;
//       blocks 512..767 -> W2i rows; blocks 768..831 -> W0 rows.
// ---------------------------------------------------------------------------
__global__ void made_prep(
    const float* __restrict__ muW0, const float* __restrict__ mub0,
    const float* __restrict__ muW1, const float* __restrict__ mub1,
    const float* __restrict__ muW2,
    const float* __restrict__ lvW0, const float* __restrict__ lvb0,
    const float* __restrict__ lvW1, const float* __restrict__ lvb1,
    const float* __restrict__ lvW2,
    float* __restrict__ ws)
{
    const int t = threadIdx.x;           // 0..63
    const int b = blockIdx.x;
    __shared__ float rowbuf[HH];

    if (b < 512) {
        const int n = b >> 8, p = b & 255;
        const int h = made_pi(p);
        const float* W1 = n ? lvW1 : muW1;
        float* o = ws + (size_t)n * NETF;
        *reinterpret_cast<float4*>(&rowbuf[4 * t]) =
            *reinterpret_cast<const float4*>(W1 + h * HH + 4 * t);
        __syncthreads();
        float4 w;
        w.x = rowbuf[made_pi(4 * t + 0)];
        w.y = rowbuf[made_pi(4 * t + 1)];
        w.z = rowbuf[made_pi(4 * t + 2)];
        w.w = rowbuf[made_pi(4 * t + 3)];
        *reinterpret_cast<float4*>(o + NW0 + p * HH + 4 * t) = w;
        if (t == 0) {
            o[NW0 + NW1 + p]      = (n ? lvb0 : mub0)[h];
            o[NW0 + NW1 + HH + p] = (n ? lvb1 : mub1)[h];
        }
    } else if (b < 768) {
        const int p = b - 512;           // sorted position
        const int h = made_pi(p);
        const int n = t >> 5, dd = t & 31;
        ws[W2IOFF + p * 64 + t] = (n ? lvW2 : muW2)[h * DD + dd];
    } else {
        const int idx = b - 768;         // 0..63
        const int n = idx >> 5, i = idx & 31;
        const float* W0 = n ? lvW0 : muW0;
        float* o = ws + (size_t)n * NETF;
        *reinterpret_cast<float4*>(&rowbuf[4 * t]) =
            *reinterpret_cast<const float4*>(W0 + i * HH + 4 * t);
        __syncthreads();
        float4 w;
        w.x = rowbuf[made_pi(4 * t + 0)];
        w.y = rowbuf[made_pi(4 * t + 1)];
        w.z = rowbuf[made_pi(4 * t + 2)];
        w.w = rowbuf[made_pi(4 * t + 3)];
        *reinterpret_cast<float4*>(o + i * HH + 4 * t) = w;
    }
}

// ---------------------------------------------------------------------------
// Main, R11 = R7 (best structure: per-wave burst loads, barrier-free,
// uniform-9 groups) + two deltas:
//  1. w0/w1 burst loads exec-masked with (lane >= ls): retired lanes' h0/h1
//     are dead, so their loads were pure L1/L2 waste — ~50% byte cut on avg.
//     Garbage in masked lanes' weight regs feeds only dead h0/h1 (A/Bf
//     writers always satisfy lane >= ls). W2 loads stay unmasked (all lanes'
//     acc is live).
//  2. divide -> (x-mu)*exp(-ls) (shorter serial output chain; eps 1e-12
//     relative, R10-validated).
// NO software pipelining: R8/R10 proved a second resident weight set spills.
// ---------------------------------------------------------------------------
__global__ __launch_bounds__(256, 2) void made_main(
    const float* __restrict__ ws, const float* __restrict__ x,
    const float* __restrict__ mub2, const float* __restrict__ lvb2,
    float* __restrict__ out)
{
    const int lane = threadIdx.x & 63;
    const int wv   = threadIdx.x >> 6;
    const int row0 = ((blockIdx.x << 2) + wv) * RR;
    const int c4   = lane << 2;          // base sorted position (4 slots/lane)
    const int nn   = lane >> 5;          // net of this lane's output acc
    const int ddl  = lane & 31;          // output dim of this lane's acc

    const float* W0p[2] = {ws,       ws + NETF};
    const float* W1p[2] = {ws + NW0, ws + NETF + NW0};
    const float* W2i    = ws + W2IOFF;

    __shared__ float A [4][2][RR][12];   // relu(h0) of finalizing group
    __shared__ float Bf[4][2][RR][12];   // relu(h1) of finalizing group

    float h0[2][4][RR], h1[2][4][RR];
    #pragma unroll
    for (int n = 0; n < 2; ++n) {
        const float* bb = ws + (size_t)n * NETF + NW0 + NW1;
        const float4 v0 = *reinterpret_cast<const float4*>(bb + c4);
        const float4 v1 = *reinterpret_cast<const float4*>(bb + HH + c4);
        const float a0[4] = {v0.x, v0.y, v0.z, v0.w};
        const float a1[4] = {v1.x, v1.y, v1.z, v1.w};
        #pragma unroll
        for (int s = 0; s < 4; ++s)
            #pragma unroll
            for (int r = 0; r < RR; ++r) { h0[n][s][r] = a0[s]; h1[n][s][r] = a1[s]; }
    }

    const float accinit = nn ? lvb2[ddl] : mub2[ddl];
    float acc[RR];
    #pragma unroll
    for (int r = 0; r < RR; ++r) acc[r] = accinit;

    float xvr[RR];
    #pragma unroll
    for (int r = 0; r < RR; ++r) xvr[r] = x[(row0 + r) * DD + ddl];

    float yprev[RR], lsum[RR], ysave[RR];
    #pragma unroll
    for (int r = 0; r < RR; ++r) { lsum[r] = 0.f; ysave[r] = 0.f; }

    // ---- step d = 0 (acc == b2) ----
    #pragma unroll
    for (int r = 0; r < RR; ++r) {
        const float mu  = __shfl(acc[r], 0, 64);
        const float lv  = __shfl(acc[r], 32, 64);
        const float ls2 = 0.5f * lv;
        lsum[r] += ls2;
        const float yd = (__shfl(xvr[r], 0, 64) - mu) * __expf(-ls2);
        yprev[r] = yd;
        if (lane == 0) ysave[r] = yd;
    }

    for (int d = 1; d < DD; ++d) {
        const int off = made_off(d);
        const int nk  = (d <= 8) ? 9 : 8;           // group size
        const int ls  = off >> 2;                   // first non-retired lane
        int r8 = off + 8; if (r8 > 255) r8 = 255;   // clamped 9th row (x0 for d>=9)

        // ======= burst-issue weight loads, MASKED to non-retired lanes =====
        float4 w0m, w0l, w1m[9], w1l[9];
        if (lane >= ls) {
            w0m = *reinterpret_cast<const float4*>(W0p[0] + (d - 1) * HH + c4);
            w0l = *reinterpret_cast<const float4*>(W0p[1] + (d - 1) * HH + c4);
            const float* a = W1p[0] + off * HH + c4;
            const float* b = W1p[1] + off * HH + c4;
            #pragma unroll
            for (int k = 0; k < 8; ++k) {
                w1m[k] = *reinterpret_cast<const float4*>(a + k * HH);
                w1l[k] = *reinterpret_cast<const float4*>(b + k * HH);
            }
            w1m[8] = *reinterpret_cast<const float4*>(W1p[0] + r8 * HH + c4);
            w1l[8] = *reinterpret_cast<const float4*>(W1p[1] + r8 * HH + c4);
        }
        float w2[9];   // unmasked: every lane's acc is a live output
        {
            const float* w2c = W2i + off * 64 + lane;
            #pragma unroll
            for (int k = 0; k < 8; ++k) w2[k] = w2c[k * 64];
            w2[8] = W2i[r8 * 64 + lane];
        }

        // ================= h0 += y_{d-1} * W0s[d-1,:] ======================
        // (retired lanes FMA garbage into dead registers — harmless)
        #pragma unroll
        for (int r = 0; r < RR; ++r) {
            h0[0][0][r] = fmaf(yprev[r], w0m.x, h0[0][0][r]);
            h0[0][1][r] = fmaf(yprev[r], w0m.y, h0[0][1][r]);
            h0[0][2][r] = fmaf(yprev[r], w0m.z, h0[0][2][r]);
            h0[0][3][r] = fmaf(yprev[r], w0m.w, h0[0][3][r]);
            h0[1][0][r] = fmaf(yprev[r], w0l.x, h0[1][0][r]);
            h0[1][1][r] = fmaf(yprev[r], w0l.y, h0[1][1][r]);
            h0[1][2][r] = fmaf(yprev[r], w0l.z, h0[1][2][r]);
            h0[1][3][r] = fmaf(yprev[r], w0l.w, h0[1][3][r]);
        }

        // zero the k=8 broadcast slots when the group has only 8 members
        // (persists: finalize writes below are bounded by nk=8 for d>=9)
        if (d >= 9 && lane == 0) {
            #pragma unroll
            for (int n = 0; n < 2; ++n)
                #pragma unroll
                for (int r = 0; r < RR; ++r) {
                    A[wv][n][r][8]  = 0.f;
                    Bf[wv][n][r][8] = 0.f;
                }
        }
        // finalize relu(h0) -> A (ONLY the nk members of group d; all >= ls)
        #pragma unroll
        for (int s = 0; s < 4; ++s) {
            const int k = c4 + s - off;
            if ((unsigned)k < (unsigned)nk) {
                #pragma unroll
                for (int r = 0; r < RR; ++r) {
                    A[wv][0][r][k] = fmaxf(h0[0][s][r], 0.f);
                    A[wv][1][r][k] = fmaxf(h0[1][s][r], 0.f);
                }
            }
        }
        // read broadcast av (wave-private LDS; program order guarantees vis.)
        float av[2][RR][9];
        #pragma unroll
        for (int n = 0; n < 2; ++n)
            #pragma unroll
            for (int r = 0; r < RR; ++r) {
                const float4 a03 = *reinterpret_cast<const float4*>(&A[wv][n][r][0]);
                const float4 a47 = *reinterpret_cast<const float4*>(&A[wv][n][r][4]);
                av[n][r][0] = a03.x; av[n][r][1] = a03.y;
                av[n][r][2] = a03.z; av[n][r][3] = a03.w;
                av[n][r][4] = a47.x; av[n][r][5] = a47.y;
                av[n][r][6] = a47.z; av[n][r][7] = a47.w;
                av[n][r][8] = A[wv][n][r][8];
            }

        // ================= h1 += av[k] * W1s[row k] — uniform 9 ============
        #pragma unroll
        for (int k = 0; k < 9; ++k) {
            #pragma unroll
            for (int r = 0; r < RR; ++r) {
                h1[0][0][r] = fmaf(av[0][r][k], w1m[k].x, h1[0][0][r]);
                h1[0][1][r] = fmaf(av[0][r][k], w1m[k].y, h1[0][1][r]);
                h1[0][2][r] = fmaf(av[0][r][k], w1m[k].z, h1[0][2][r]);
                h1[0][3][r] = fmaf(av[0][r][k], w1m[k].w, h1[0][3][r]);
                h1[1][0][r] = fmaf(av[1][r][k], w1l[k].x, h1[1][0][r]);
                h1[1][1][r] = fmaf(av[1][r][k], w1l[k].y, h1[1][1][r]);
                h1[1][2][r] = fmaf(av[1][r][k], w1l[k].z, h1[1][2][r]);
                h1[1][3][r] = fmaf(av[1][r][k], w1l[k].w, h1[1][3][r]);
            }
        }

        // finalize relu(h1) -> Bf (ONLY the nk members of group d)
        #pragma unroll
        for (int s = 0; s < 4; ++s) {
            const int k = c4 + s - off;
            if ((unsigned)k < (unsigned)nk) {
                #pragma unroll
                for (int r = 0; r < RR; ++r) {
                    Bf[wv][0][r][k] = fmaxf(h1[0][s][r], 0.f);
                    Bf[wv][1][r][k] = fmaxf(h1[1][s][r], 0.f);
                }
            }
        }
        // fold finalized relu(h1) into output accumulators
        float rb[RR][9];
        #pragma unroll
        for (int r = 0; r < RR; ++r) {
            const float4 b03 = *reinterpret_cast<const float4*>(&Bf[wv][nn][r][0]);
            const float4 b47 = *reinterpret_cast<const float4*>(&Bf[wv][nn][r][4]);
            rb[r][0] = b03.x; rb[r][1] = b03.y; rb[r][2] = b03.z; rb[r][3] = b03.w;
            rb[r][4] = b47.x; rb[r][5] = b47.y; rb[r][6] = b47.z; rb[r][7] = b47.w;
            rb[r][8] = Bf[wv][nn][r][8];
        }
        #pragma unroll
        for (int k = 0; k < 9; ++k)
            #pragma unroll
            for (int r = 0; r < RR; ++r)
                acc[r] = fmaf(rb[r][k], w2[k], acc[r]);

        // ================= outputs for dim d ===============================
        #pragma unroll
        for (int r = 0; r < RR; ++r) {
            const float mu  = __shfl(acc[r], d, 64);
            const float lv  = __shfl(acc[r], 32 + d, 64);
            const float ls2 = 0.5f * lv;
            lsum[r] += ls2;
            const float yd = (__shfl(xvr[r], d, 64) - mu) * __expf(-ls2);
            yprev[r] = yd;
            if (lane == d) ysave[r] = yd;
        }
    }

    #pragma unroll
    for (int r = 0; r < RR; ++r) {
        if (lane < DD) out[(row0 + r) * DD + lane] = ysave[r];   // coalesced
        if (lane == 0) out[BB * DD + row0 + r] = lsum[r];
    }
}

// ---------------------------------------------------------------------------
// Fallback (no workspace): R1-style kernel.
// ---------------------------------------------------------------------------
__global__ __launch_bounds__(64, 1) void made_inv_fb(
    const float* __restrict__ x,
    const float* __restrict__ muW0, const float* __restrict__ mub0,
    const float* __restrict__ muW1, const float* __restrict__ mub1,
    const float* __restrict__ muW2, const float* __restrict__ mub2,
    const float* __restrict__ lvW0, const float* __restrict__ lvb0,
    const float* __restrict__ lvW1, const float* __restrict__ lvb1,
    const float* __restrict__ lvW2, const float* __restrict__ lvb2,
    float* __restrict__ out)
{
    const int lane    = threadIdx.x;
    const int rowBase = blockIdx.x * 4;
    const int hb      = lane << 2;
    int deg[4];
    #pragma unroll
    for (int s = 0; s < 4; ++s) deg[s] = ((hb + s) % 31) + 1;
    const float* Wp0[2] = {muW0, lvW0};
    const float* Bp0[2] = {mub0, lvb0};
    const float* Wp1[2] = {muW1, lvW1};
    const float* Bp1[2] = {mub1, lvb1};
    const float* Wp2[2] = {muW2, lvW2};
    float h0pre[2][4][4], h1pre[2][4][4], r1[2][4][4], yprev[4], lsum[4];
    #pragma unroll
    for (int n = 0; n < 2; ++n) {
        const float4 b0v = *reinterpret_cast<const float4*>(Bp0[n] + hb);
        const float4 b1v = *reinterpret_cast<const float4*>(Bp1[n] + hb);
        const float b0a[4] = {b0v.x, b0v.y, b0v.z, b0v.w};
        const float b1a[4] = {b1v.x, b1v.y, b1v.z, b1v.w};
        #pragma unroll
        for (int s = 0; s < 4; ++s)
            #pragma unroll
            for (int r = 0; r < 4; ++r) {
                h0pre[n][s][r] = b0a[s]; h1pre[n][s][r] = b1a[s]; r1[n][s][r] = 0.f;
            }
    }
    #pragma unroll
    for (int r = 0; r < 4; ++r) { yprev[r] = 0.f; lsum[r] = 0.f; }
    __shared__ float lds_a[2][4][12];
    for (int d = 0; d < DD; ++d) {
        if (d >= 1) {
            #pragma unroll
            for (int n = 0; n < 2; ++n) {
                const float4 w0 = *reinterpret_cast<const float4*>(Wp0[n] + (d - 1) * HH + hb);
                const float w0a[4] = {w0.x, w0.y, w0.z, w0.w};
                #pragma unroll
                for (int s = 0; s < 4; ++s)
                    #pragma unroll
                    for (int r = 0; r < 4; ++r)
                        h0pre[n][s][r] = fmaf(yprev[r], w0a[s], h0pre[n][s][r]);
            }
            #pragma unroll
            for (int n = 0; n < 2; ++n)
                #pragma unroll
                for (int s = 0; s < 4; ++s)
                    if (deg[s] == d) {
                        const int k = (hb + s - (d - 1)) / 31;
                        #pragma unroll
                        for (int r = 0; r < 4; ++r)
                            lds_a[n][r][k] = fmaxf(h0pre[n][s][r], 0.f);
                    }
            __syncthreads();
            const bool nine = (d <= 8);
            #pragma unroll
            for (int n = 0; n < 2; ++n) {
                const float* W1r = Wp1[n] + (size_t)(d - 1) * HH + hb;
                float4 w1v[9];
                #pragma unroll
                for (int k = 0; k < 8; ++k)
                    w1v[k] = *reinterpret_cast<const float4*>(W1r + k * 31 * HH);
                if (nine) w1v[8] = *reinterpret_cast<const float4*>(W1r + 8 * 31 * HH);
                #pragma unroll
                for (int r = 0; r < 4; ++r) {
                    const float4 a03 = *reinterpret_cast<const float4*>(&lds_a[n][r][0]);
                    const float4 a47 = *reinterpret_cast<const float4*>(&lds_a[n][r][4]);
                    const float av[8] = {a03.x, a03.y, a03.z, a03.w, a47.x, a47.y, a47.z, a47.w};
                    #pragma unroll
                    for (int k = 0; k < 8; ++k) {
                        const float wk[4] = {w1v[k].x, w1v[k].y, w1v[k].z, w1v[k].w};
                        #pragma unroll
                        for (int s = 0; s < 4; ++s)
                            h1pre[n][s][r] = fmaf(av[k], wk[s], h1pre[n][s][r]);
                    }
                    if (nine) {
                        const float a8 = lds_a[n][r][8];
                        const float wk[4] = {w1v[8].x, w1v[8].y, w1v[8].z, w1v[8].w};
                        #pragma unroll
                        for (int s = 0; s < 4; ++s)
                            h1pre[n][s][r] = fmaf(a8, wk[s], h1pre[n][s][r]);
                    }
                }
            }
            #pragma unroll
            for (int n = 0; n < 2; ++n)
                #pragma unroll
                for (int s = 0; s < 4; ++s)
                    if (deg[s] == d)
                        #pragma unroll
                        for (int r = 0; r < 4; ++r)
                            r1[n][s][r] = fmaxf(h1pre[n][s][r], 0.f);
            __syncthreads();
        }
        float w2v[2][4];
        #pragma unroll
        for (int n = 0; n < 2; ++n)
            #pragma unroll
            for (int s = 0; s < 4; ++s)
                w2v[n][s] = Wp2[n][(hb + s) * DD + d];
        float red[2][4];
        #pragma unroll
        for (int n = 0; n < 2; ++n)
            #pragma unroll
            for (int r = 0; r < 4; ++r) {
                float p = 0.f;
                #pragma unroll
                for (int s = 0; s < 4; ++s) p = fmaf(r1[n][s][r], w2v[n][s], p);
                red[n][r] = p;
            }
        #pragma unroll
        for (int m = 1; m < 64; m <<= 1)
            #pragma unroll
            for (int n = 0; n < 2; ++n)
                #pragma unroll
                for (int r = 0; r < 4; ++r)
                    red[n][r] += __shfl_xor(red[n][r], m, 64);
        const float b2m = mub2[d], b2l = lvb2[d];
        #pragma unroll
        for (int r = 0; r < 4; ++r) {
            const float mu = red[0][r] + b2m;
            const float logstd = 0.5f * (red[1][r] + b2l);
            lsum[r] += logstd;
            const float yd = (x[(rowBase + r) * DD + d] - mu) / (__expf(logstd) + EPSF);
            yprev[r] = yd;
            if (lane == 0) out[(rowBase + r) * DD + d] = yd;
        }
    }
    if (lane == 0)
        #pragma unroll
        for (int r = 0; r < 4; ++r) out[BB * DD + rowBase + r] = lsum[r];
}

extern "C" void kernel_launch(void* const* d_in, const int* in_sizes, int n_in,
                              void* d_out, int out_size, void* d_ws, size_t ws_size,
                              hipStream_t stream) {
    const float* x    = (const float*)d_in[0];
    const float* muW0 = (const float*)d_in[1];
    const float* mub0 = (const float*)d_in[2];
    const float* muW1 = (const float*)d_in[3];
    const float* mub1 = (const float*)d_in[4];
    const float* muW2 = (const float*)d_in[5];
    const float* mub2 = (const float*)d_in[6];
    const float* lvW0 = (const float*)d_in[7];
    const float* lvb0 = (const float*)d_in[8];
    const float* lvW1 = (const float*)d_in[9];
    const float* lvb1 = (const float*)d_in[10];
    const float* lvW2 = (const float*)d_in[11];
    const float* lvb2 = (const float*)d_in[12];
    float* out = (float*)d_out;

    if (ws_size >= WSNEED) {
        float* ws = (float*)d_ws;
        made_prep<<<dim3(832), dim3(64), 0, stream>>>(
            muW0, mub0, muW1, mub1, muW2,
            lvW0, lvb0, lvW1, lvb1, lvW2, ws);
        made_main<<<dim3(BB / (4 * RR)), dim3(256), 0, stream>>>(ws, x, mub2, lvb2, out);
    } else {
        made_inv_fb<<<dim3(BB / 4), dim3(64), 0, stream>>>(x,
            muW0, mub0, muW1, mub1, muW2, mub2,
            lvW0, lvb0, lvW1, lvb1, lvW2, lvb2, out);
    }
}